// Round 10
// baseline (888.426 us; speedup 1.0000x reference)
//
#include <hip/hip_runtime.h>
#include <hip/hip_bf16.h>
#include <hip/hip_cooperative_groups.h>
#include <math.h>

namespace cg = cooperative_groups;

typedef __hip_bfloat16 bf16;
typedef __attribute__((ext_vector_type(8))) short short8;
typedef __attribute__((ext_vector_type(4))) float float4v;

static constexpr int Bb = 32, Nn = 256, Hh = 1024, HEADS = 8, NHID = 128, NCLS = 7, BAND = 24;
static constexpr int M = Bb * Nn;         // 8192 rows
static constexpr float ALPHA = 0.2f;
static constexpr long INEL = (long)M * Hh;   // 8388608 elements per hidden input

__device__ __forceinline__ float tof(bf16 x) { return __bfloat162float(x); }
__device__ __forceinline__ bf16 tob(float x) { return __float2bfloat16(x); }
__device__ __forceinline__ unsigned short f2bits(float x) {
    bf16 h = __float2bfloat16(x);
    return *(unsigned short*)&h;
}
__device__ __forceinline__ float bits2f(unsigned short u) {
    unsigned v = ((unsigned)u) << 16;
    float f;
    __builtin_memcpy(&f, &v, 4);
    return f;
}

// async global->LDS, 16B per lane; data lands at lptr + lane*16 (wave-uniform base)
__device__ __forceinline__ void gload16(const void* g, void* l) {
    __builtin_amdgcn_global_load_lds(
        (const __attribute__((address_space(1))) void*)g,
        (__attribute__((address_space(3))) void*)l, 16, 0, 0);
}

// -------- canonical bf16 weight arena (element offsets); big matrices TRANSPOSED ---
static constexpr long OFF_PWT  = 0;                 // pooler_W^T  [1024 n][1024 k]
static constexpr long OFF_PB   = 1048576;           // pooler_b  [1024]
static constexpr long OFF_WCT  = 1049600;           // gat_W -> Wcat^T [1024 n][1024 f]
static constexpr long OFF_GA1  = 2098176;           // gat_a1 [8,128]
static constexpr long OFF_GA2  = 2099200;
static constexpr long OFF_OWT  = 2100224;           // out_W^T [1024,1024]
static constexpr long OFF_OA1  = 3148800;           // out_a1 [1024]
static constexpr long OFF_OA2  = 3149824;
static constexpr long OFF_CWT  = 6298624;           // cls_W^T [7][1024]
static constexpr long OFF_CB   = 6305792;           // cls_b [7]
static constexpr long OFF_HA   = 6305799;           // hmm_A [7,7]
static constexpr long W_TOTAL  = 6305848;

static constexpr int SLOT_US = 256 * 32;     // 8192 ushorts = 16KB per GEMM ring slot

__device__ __forceinline__ float ldany(const void* p, long i, int isb) {
    return isb ? tof(((const bf16*)p)[i]) : ((const float*)p)[i];
}

// LDS union: max member 52928 B -> 3 blocks/CU (158784 <= 163840)
union ShU {
    int sb[256];
    unsigned short gemm[3 * SLOT_US];                            // 49152 B
    float prep[7168];                                            // 28672 B
    struct { unsigned short S[152][128];
             float f1s[152], f2s[152];
             float att[128][25]; } a1;                           // 52928 B
    struct { unsigned short S[152][128];
             float att[128][25];
             float AT[NCLS][NCLS]; } a2;
    float ps[4];
    float red[256];
};

struct MegaArgs {
    const void *pW, *pb, *gW, *ga1, *ga2, *oW, *oa1, *oa2;
    const void *l1W, *l1b, *l0W, *l0b, *cW, *cb, *hA;
    const void *in_emo, *in_cls;
    const int* labels;
    bf16 *wc, *C, *E, *Wb, *H2;
    float *f1b, *f2b, *blocksum, *Bprob, *lhmm, *W1T, *W2T, *Gb, *cvec;
    void* out;
};

// block-local dtype probe (first 8KB of pooler_W); trailing barrier frees scratch
__device__ __forceinline__ int probe_dev(const void* pW, int t, int* sb) {
    int bad = 0;
    for (int i = t; i < 4096; i += 256) {
        float v = tof(((const bf16*)pW)[i]);
        if (!(fabsf(v) < 1e4f)) bad = 1;
    }
    sb[t] = bad; __syncthreads();
    for (int s = 128; s; s >>= 1) { if (t < s) sb[t] |= sb[t + s]; __syncthreads(); }
    int isb = sb[0] ? 0 : 1;
    __syncthreads();
    return isb;
}

// ---- small weights (pure global; one block) ---------------------------------------
__device__ void smalls_task(const MegaArgs& a, int t, int isb) {
    bf16* wc = a.wc;
    for (int i = t; i < 1024; i += 256) {
        wc[OFF_PB  + i] = tob(ldany(a.pb,  i, isb));
        wc[OFF_GA1 + i] = tob(ldany(a.ga1, i, isb));
        wc[OFF_GA2 + i] = tob(ldany(a.ga2, i, isb));
        wc[OFF_OA1 + i] = tob(ldany(a.oa1, i, isb));
        wc[OFF_OA2 + i] = tob(ldany(a.oa2, i, isb));
    }
    for (int i = t; i < 7168; i += 256) {
        int c = i >> 10, k = i & 1023;
        wc[OFF_CWT + i] = tob(ldany(a.cW, (long)k * 7 + c, isb));
    }
    if (t < NCLS) wc[OFF_CB + t] = tob(ldany(a.cb, t, isb));
    if (t < NCLS * NCLS) wc[OFF_HA + t] = tob(ldany(a.hA, t, isb));
}

// ---- transposes (v<2560) + gvec (v>=2560) -----------------------------------------
__device__ void prep_mid_task(int v, const MegaArgs& a, int t, int isb, ShU* sh) {
    if (v < 2560) {
        int z = v >> 8, rem = v & 255;
        int bxx = rem & 15, byy = rem >> 4;
        float (*S)[65] = (float(*)[65])sh->prep;
        const int tx = t & 63, ty0 = t >> 6;
        if (z < 2) {
            const void* src = z ? a.oW : a.pW;
            const long doff = z ? OFF_OWT : OFF_PWT;
            const int r0 = byy * 64, c0 = bxx * 64;
            #pragma unroll 4
            for (int it = 0; it < 16; ++it) {
                int ty = it * 4 + ty0;
                S[ty][tx] = ldany(src, (long)(r0 + ty) * 1024 + c0 + tx, isb);
            }
            __syncthreads();
            #pragma unroll 4
            for (int it = 0; it < 16; ++it) {
                int ty = it * 4 + ty0;
                a.wc[doff + (long)(c0 + ty) * 1024 + r0 + tx] = tob(S[tx][ty]);
            }
        } else {
            if (bxx >= 2) return;
            const int h = z - 2;
            const int r0 = byy * 64, c0 = bxx * 64;
            const long sbase = (long)h * 131072;
            #pragma unroll 4
            for (int it = 0; it < 16; ++it) {
                int ty = it * 4 + ty0;
                S[ty][tx] = ldany(a.gW, sbase + (long)(r0 + ty) * 128 + c0 + tx, isb);
            }
            __syncthreads();
            #pragma unroll 4
            for (int it = 0; it < 16; ++it) {
                int ty = it * 4 + ty0;
                a.wc[OFF_WCT + (long)(h * 128 + c0 + ty) * 1024 + r0 + tx] = tob(S[tx][ty]);
            }
        }
        return;
    }
    // gvec: G = lin0_W @ cls_W   (256 vtasks)
    int bi = v - 2560;
    float (*S)[NCLS] = (float(*)[NCLS])sh->prep;
    for (int j = t; j < 1024; j += 256) {
        #pragma unroll
        for (int c = 0; c < NCLS; ++c) S[j][c] = ldany(a.cW, (long)j * 7 + c, isb);
    }
    __syncthreads();
    const int wave = t >> 6, lane = t & 63;
    #pragma unroll
    for (int r = 0; r < 2; ++r) {
        int k = bi * 8 + wave * 2 + r;
        float acc[NCLS];
        #pragma unroll
        for (int c = 0; c < NCLS; ++c) acc[c] = 0.f;
        #pragma unroll
        for (int q = 0; q < 16; ++q) {
            int j = lane * 16 + q;
            float x = ldany(a.l0W, (long)k * 1024 + j, isb);
            #pragma unroll
            for (int c = 0; c < NCLS; ++c) acc[c] += x * S[j][c];
        }
        #pragma unroll
        for (int c = 0; c < NCLS; ++c)
            #pragma unroll
            for (int off = 32; off; off >>= 1) acc[c] += __shfl_down(acc[c], off);
        if (lane == 0) {
            #pragma unroll
            for (int c = 0; c < NCLS; ++c) {
                if (k < 1024) a.W1T[c * 1024 + k] = acc[c];
                else          a.Gb[(k - 1024) * 7 + c] = acc[c];
            }
        }
    }
}

// ---- w2 (128 vtasks) --------------------------------------------------------------
__device__ void w2_task(int bi, const MegaArgs& a, int t, int isb, ShU* sh) {
    float (*S)[NCLS] = (float(*)[NCLS])sh->prep;
    for (int j = t; j < 1024; j += 256) {
        #pragma unroll
        for (int c = 0; c < NCLS; ++c) S[j][c] = a.Gb[(long)j * 7 + c];
    }
    __syncthreads();
    const int wave = t >> 6, lane = t & 63;
    #pragma unroll
    for (int r = 0; r < 2; ++r) {
        int i = bi * 8 + wave * 2 + r;
        float acc[NCLS];
        #pragma unroll
        for (int c = 0; c < NCLS; ++c) acc[c] = 0.f;
        #pragma unroll
        for (int q = 0; q < 16; ++q) {
            int o = lane * 16 + q;
            float x = ldany(a.l1W, (long)i * 1024 + o, isb);
            #pragma unroll
            for (int c = 0; c < NCLS; ++c) acc[c] += x * S[o][c];
        }
        #pragma unroll
        for (int c = 0; c < NCLS; ++c)
            #pragma unroll
            for (int off = 32; off; off >>= 1) acc[c] += __shfl_down(acc[c], off);
        if (lane == 0) {
            #pragma unroll
            for (int c = 0; c < NCLS; ++c) a.W2T[c * 1024 + i] = acc[c];
        }
    }
}

// ---- cvec (1 vtask; one wave) -----------------------------------------------------
__device__ void cvec_task(const MegaArgs& a, int t, int isb) {
    if (t >= 64) return;
    int lane = t;
    float acc[NCLS];
    #pragma unroll
    for (int c = 0; c < NCLS; ++c) acc[c] = 0.f;
    for (int o = lane; o < 1024; o += 64) {
        float b1 = ldany(a.l1b, o, isb);
        float b0 = ldany(a.l0b, o, isb);
        #pragma unroll
        for (int c = 0; c < NCLS; ++c)
            acc[c] += b1 * a.Gb[o * 7 + c] + b0 * ldany(a.cW, (long)o * 7 + c, isb);
    }
    #pragma unroll
    for (int c = 0; c < NCLS; ++c)
        #pragma unroll
        for (int off = 32; off; off >>= 1) acc[c] += __shfl_down(acc[c], off);
    if (lane == 0) {
        #pragma unroll
        for (int c = 0; c < NCLS; ++c) a.cvec[c] = acc[c] + ldany(a.cb, c, isb);
    }
}

// ================= MFMA GEMM core (R2 reg-dbuf + 3-slot ring; unchanged) ===========
template <int ACT, int DOTS>
__device__ __forceinline__ void gemm_pipe_core(
    const bf16* __restrict__ A, int strideA,
    const bf16* __restrict__ Bt, int strideB,
    const bf16* __restrict__ bias, bf16* __restrict__ Cout,
    int Nc, int K, int bm, int bn, unsigned short* lds,
    const bf16* __restrict__ oa1 = nullptr, const bf16* __restrict__ oa2 = nullptr,
    float* __restrict__ f1b = nullptr, float* __restrict__ f2b = nullptr) {
    const int tid = threadIdx.x;
    const int lane = tid & 63;
    const int wave = tid >> 6;
    const int wm = (wave >> 1) * 64, wn = (wave & 1) * 64;
    const int l15 = lane & 15, quad = lane >> 4;
    const int csw = ((lane & 3) ^ ((lane >> 2) & 3) ^ (lane >> 4)) * 8;
    const int sc8 = (quad ^ (l15 & 3) ^ (l15 >> 2)) * 8;

    long aoff[2], boff[2];
    #pragma unroll
    for (int o = 0; o < 2; ++o) {
        aoff[o] = (long)(bm + wave * 32 + o * 16 + (lane >> 2)) * strideA + csw;
        boff[o] = (long)(bn + wave * 32 + o * 16 + (lane >> 2)) * strideB + csw;
    }
    const int aDst = wave * 32 * 32;
    const int bDst = (128 + wave * 32) * 32;

    const int nt = K / 32;
    float4v acc[4][4];
    #pragma unroll
    for (int i = 0; i < 4; ++i)
        #pragma unroll
        for (int j = 0; j < 4; ++j) acc[i][j] = (float4v){0.f, 0.f, 0.f, 0.f};

    auto stage = [&](int ts, int slot) {
        unsigned short* buf = lds + slot * SLOT_US;
        int k = ts * 32;
        gload16(A + aoff[0] + k, buf + aDst);
        gload16(A + aoff[1] + k, buf + aDst + 512);
        gload16(Bt + boff[0] + k, buf + bDst);
        gload16(Bt + boff[1] + k, buf + bDst + 512);
    };
    auto frags = [&](int slot, short8* af, short8* bfr) {
        const unsigned short* bufc = lds + slot * SLOT_US;
        #pragma unroll
        for (int i = 0; i < 4; ++i)
            af[i] = *(const short8*)(bufc + (wm + i * 16 + l15) * 32 + sc8);
        #pragma unroll
        for (int j = 0; j < 4; ++j)
            bfr[j] = *(const short8*)(bufc + (128 + wn + j * 16 + l15) * 32 + sc8);
    };

    stage(0, 0); stage(1, 1); stage(2, 2);
    asm volatile("s_waitcnt vmcnt(8)" ::: "memory");
    __builtin_amdgcn_s_barrier();
    asm volatile("" ::: "memory");
    short8 afA[4], bfA[4], afB[4], bfB[4];
    frags(0, afA, bfA);
    int c0 = 0, c1 = 1, c2 = 2;

    for (int t = 0; t < nt; t += 2) {
        asm volatile("s_waitcnt lgkmcnt(0)" ::: "memory");
        if (t < nt - 2) asm volatile("s_waitcnt vmcnt(4)" ::: "memory");
        else            asm volatile("s_waitcnt vmcnt(0)" ::: "memory");
        __builtin_amdgcn_s_barrier();
        asm volatile("" ::: "memory");
        if (t + 3 < nt) stage(t + 3, c0);
        if (t + 1 < nt) frags(c1, afB, bfB);
        __builtin_amdgcn_s_setprio(1);
        #pragma unroll
        for (int i = 0; i < 4; ++i)
            #pragma unroll
            for (int j = 0; j < 4; ++j)
                acc[i][j] = __builtin_amdgcn_mfma_f32_16x16x32_bf16(afA[i], bfA[j], acc[i][j], 0, 0, 0);
        __builtin_amdgcn_s_setprio(0);
        asm volatile("" ::: "memory");
        asm volatile("s_waitcnt lgkmcnt(0)" ::: "memory");
        if (t + 1 < nt - 2) asm volatile("s_waitcnt vmcnt(4)" ::: "memory");
        else                asm volatile("s_waitcnt vmcnt(0)" ::: "memory");
        __builtin_amdgcn_s_barrier();
        asm volatile("" ::: "memory");
        if (t + 4 < nt) stage(t + 4, c1);
        if (t + 2 < nt) frags(c2, afA, bfA);
        __builtin_amdgcn_s_setprio(1);
        #pragma unroll
        for (int i = 0; i < 4; ++i)
            #pragma unroll
            for (int j = 0; j < 4; ++j)
                acc[i][j] = __builtin_amdgcn_mfma_f32_16x16x32_bf16(afB[i], bfB[j], acc[i][j], 0, 0, 0);
        __builtin_amdgcn_s_setprio(0);
        asm volatile("" ::: "memory");
        int n0 = c2, n1 = c0, n2 = c1;
        c0 = n0; c1 = n1; c2 = n2;
    }

    #pragma unroll
    for (int j = 0; j < 4; ++j) {
        int gn = bn + wn + j * 16 + l15;
        float bj = bias ? tof(bias[gn]) : 0.f;
        #pragma unroll
        for (int i = 0; i < 4; ++i) {
            #pragma unroll
            for (int r = 0; r < 4; ++r) {
                int gm = bm + wm + i * 16 + quad * 4 + r;
                float v = acc[i][j][r] + bj;
                if (ACT == 1) v = tanhf(v);
                Cout[(long)gm * Nc + gn] = tob(v);
            }
        }
    }
    if (DOTS) {
        float o1v[4], o2v[4];
        #pragma unroll
        for (int j = 0; j < 4; ++j) {
            int gn = bn + wn + j * 16 + l15;
            o1v[j] = tof(oa1[gn]); o2v[j] = tof(oa2[gn]);
        }
        #pragma unroll
        for (int i = 0; i < 4; ++i) {
            #pragma unroll
            for (int r = 0; r < 4; ++r) {
                int gm = bm + wm + i * 16 + quad * 4 + r;
                float p1 = 0.f, p2 = 0.f;
                #pragma unroll
                for (int j = 0; j < 4; ++j) {
                    float v = bits2f(f2bits(acc[i][j][r]));
                    p1 += v * o1v[j]; p2 += v * o2v[j];
                }
                #pragma unroll
                for (int m = 1; m < 16; m <<= 1) {
                    p1 += __shfl_xor(p1, m); p2 += __shfl_xor(p2, m);
                }
                if (l15 == 0) { atomicAdd(&f1b[gm], p1); atomicAdd(&f2b[gm], p2); }
            }
        }
    }
}

// ---- cls7 vtask: 4 rows (wave per row) --------------------------------------------
__device__ void cls7_task(int vt, const bf16* X, const bf16* Wt, const bf16* cb,
                          float* Bout, int t) {
    const int wave = t >> 6, lane = t & 63;
    const int row = vt * 4 + wave;
    float xv[16];
    {
        const bf16* x = X + (long)row * Hh + lane * 16;
        union { int4 v; unsigned short us[8]; } u0, u1;
        u0.v = *(const int4*)x; u1.v = *(const int4*)(x + 8);
        #pragma unroll
        for (int q = 0; q < 8; ++q) { xv[q] = bits2f(u0.us[q]); xv[q + 8] = bits2f(u1.us[q]); }
    }
    float acc[NCLS];
    #pragma unroll
    for (int cc = 0; cc < NCLS; ++cc) {
        const bf16* wr = Wt + (long)cc * Hh + lane * 16;
        union { int4 v; unsigned short us[8]; } w0, w1;
        w0.v = *(const int4*)wr; w1.v = *(const int4*)(wr + 8);
        float s = 0.f;
        #pragma unroll
        for (int q = 0; q < 8; ++q) {
            s += xv[q] * bits2f(w0.us[q]);
            s += xv[q + 8] * bits2f(w1.us[q]);
        }
        acc[cc] = s;
    }
    #pragma unroll
    for (int cc = 0; cc < NCLS; ++cc)
        #pragma unroll
        for (int off = 32; off; off >>= 1) acc[cc] += __shfl_down(acc[cc], off);
    if (lane == 0) {
        float mx = -1e30f;
        #pragma unroll
        for (int cc = 0; cc < NCLS; ++cc) { acc[cc] += tof(cb[cc]); mx = fmaxf(mx, acc[cc]); }
        float s = 0.f;
        #pragma unroll
        for (int cc = 0; cc < NCLS; ++cc) { acc[cc] = expf(acc[cc] - mx); s += acc[cc]; }
        float inv = 1.0f / s;
        #pragma unroll
        for (int cc = 0; cc < NCLS; ++cc) Bout[(long)row * NCLS + cc] = acc[cc] * inv;
    }
}

// ---- att1 vtask: v<256 mean path; else attention (bxm = v-256) --------------------
__device__ void att1_task(int v, const bf16* Wh, const bf16* ga1, const bf16* ga2,
                          bf16* h1, int t, ShU* sh) {
    const int wave = t >> 6, lane = t & 63;
    if (v < 256) {
        int h = v & 7, b = v >> 3;
        float s0 = 0.f, s1 = 0.f;
        long base = (long)(b * 256) * 1024 + h * 128 + lane * 2;
        for (int m = wave * 64; m < wave * 64 + 64; ++m) {
            unsigned u = *(const unsigned*)(Wh + base + (long)m * 1024);
            s0 += bits2f((unsigned short)(u & 0xffff));
            s1 += bits2f((unsigned short)(u >> 16));
        }
        float* red = (float*)sh;
        red[(wave * 64 + lane) * 2]     = s0;
        red[(wave * 64 + lane) * 2 + 1] = s1;
        __syncthreads();
        if (wave == 0) {
            s0 = red[lane * 2] + red[(64 + lane) * 2] + red[(128 + lane) * 2] + red[(192 + lane) * 2];
            s1 = red[lane * 2 + 1] + red[(64 + lane) * 2 + 1] + red[(128 + lane) * 2 + 1] + red[(192 + lane) * 2 + 1];
            s0 *= (1.0f / 256.0f); s1 *= (1.0f / 256.0f);
            s0 = s0 > 0.f ? s0 : expm1f(s0);
            s1 = s1 > 0.f ? s1 : expm1f(s1);
            unsigned out = (unsigned)f2bits(s0) | ((unsigned)f2bits(s1) << 16);
            *(unsigned*)(h1 + base) = out;
        }
        return;
    }
    const int bxm = v - 256;
    const int b = bxm >> 4, h = (bxm >> 1) & 7, half = bxm & 1;
    const int nbase = half * 128;
    const int mstart = half ? (nbase - (BAND - 1)) : 0;
    const int mcount = half ? (256 - mstart) : 128;
    const int c = t & 15;

    float av1[8], av2[8];
    {
        union { int4 v4; unsigned short us[8]; } u1, u2;
        u1.v4 = *(const int4*)(ga1 + h * 128 + c * 8);
        u2.v4 = *(const int4*)(ga2 + h * 128 + c * 8);
        #pragma unroll
        for (int qq = 0; qq < 8; ++qq) { av1[qq] = bits2f(u1.us[qq]); av2[qq] = bits2f(u2.us[qq]); }
    }

    const int iters = (mcount * 16 + 255) >> 8;
    for (int i = 0; i < iters; ++i) {
        int li = i * 256 + t;
        int mr = li >> 4;
        if (mr < mcount) {
            long ga = (long)(b * 256 + mstart + mr) * 1024 + h * 128 + c * 8;
            union { int4 v4; unsigned short us[8]; } u;
            u.v4 = *(const int4*)(Wh + ga);
            float p1 = 0.f, p2 = 0.f;
            #pragma unroll
            for (int qq = 0; qq < 8; ++qq) {
                float f = bits2f(u.us[qq]);
                p1 += f * av1[qq]; p2 += f * av2[qq];
            }
            *(int4*)&sh->a1.S[mr][c * 8] = u.v4;
            #pragma unroll
            for (int mask = 1; mask < 16; mask <<= 1) {
                p1 += __shfl_xor(p1, mask);
                p2 += __shfl_xor(p2, mask);
            }
            if (c == 0) { sh->a1.f1s[mr] = p1; sh->a1.f2s[mr] = p2; }
        }
    }
    __syncthreads();

    if (t < 128) {
        int n = nbase + t;
        if (n > 0) {
            int cnt = n < (BAND - 1) ? n : (BAND - 1);
            int m0 = n - cnt;
            float f1n = sh->a1.f1s[n - mstart];
            float e[BAND - 1];
            float mx = -1e30f;
            for (int i = 0; i < cnt; ++i) {
                float vv = f1n + sh->a1.f2s[m0 + i - mstart];
                vv = vv > 0.f ? vv : ALPHA * vv;
                e[i] = vv; mx = fmaxf(mx, vv);
            }
            float ss = 0.f;
            for (int i = 0; i < cnt; ++i) { e[i] = __expf(e[i] - mx); ss += e[i]; }
            float inv = 1.0f / ss;
            for (int i = 0; i < cnt; ++i) sh->a1.att[t][i] = e[i] * inv;
        }
    }
    __syncthreads();

    for (int ln = wave; ln < 128; ln += 4) {
        int n = nbase + ln;
        if (n == 0) continue;
        int cnt = n < (BAND - 1) ? n : (BAND - 1);
        int mr0 = n - cnt - mstart;
        float s0 = 0.f, s1 = 0.f;
        for (int i = 0; i < cnt; ++i) {
            float aa = sh->a1.att[ln][i];
            unsigned u = *(const unsigned*)&sh->a1.S[mr0 + i][lane * 2];
            s0 += aa * bits2f((unsigned short)(u & 0xffff));
            s1 += aa * bits2f((unsigned short)(u >> 16));
        }
        s0 = s0 > 0.f ? s0 : expm1f(s0);
        s1 = s1 > 0.f ? s1 : expm1f(s1);
        unsigned out = (unsigned)f2bits(s0) | ((unsigned)f2bits(s1) << 16);
        *(unsigned*)(h1 + (long)(b * 256 + n) * 1024 + h * 128 + lane * 2) = out;
    }
}

// ---- att2 (v<512) / hmm (v>=512) vtask --------------------------------------------
__device__ void att2_hmm_task(int v, const MegaArgs& a, int t, ShU* sh) {
    const int wave = t >> 6, lane = t & 63;
    if (v >= 512) {                        // HMM: 32 vtasks x 256 rows
        if (t < NCLS * NCLS) {
            int i = t / NCLS, j = t % NCLS;
            sh->a2.AT[i][j] = tof((a.wc + OFF_HA)[j * NCLS + i]);
        }
        __syncthreads();
        int idx = (v - 512) * 256 + t;
        int n = idx & 255, b = idx >> 8;
        int t0 = n - (BAND - 1) > 0 ? n - (BAND - 1) : 0;
        const float* Bp = a.Bprob + (long)(b * 256) * NCLS;
        float p[NCLS];
        float s = 0.f;
        #pragma unroll
        for (int cc = 0; cc < NCLS; ++cc) { p[cc] = Bp[t0 * NCLS + cc]; s += p[cc]; }
        float inv = 1.0f / s;
        #pragma unroll
        for (int cc = 0; cc < NCLS; ++cc) p[cc] *= inv;
        for (int tt = t0 + 1; tt <= n; ++tt) {
            float q[NCLS]; float ss = 0.f;
            #pragma unroll
            for (int i = 0; i < NCLS; ++i) {
                float av = 0.f;
                #pragma unroll
                for (int j = 0; j < NCLS; ++j) av += sh->a2.AT[i][j] * p[j];
                av *= Bp[tt * NCLS + i];
                q[i] = av; ss += av;
            }
            float iv = 1.0f / ss;
            #pragma unroll
            for (int i = 0; i < NCLS; ++i) p[i] = q[i] * iv;
        }
        #pragma unroll
        for (int cc = 0; cc < NCLS; ++cc) a.lhmm[(long)idx * NCLS + cc] = p[cc];
        return;
    }
    const int b = v >> 4, half = (v >> 3) & 1, jt = v & 7;
    const int nbase = half * 128;
    const int mstart = half ? (nbase - (BAND - 1)) : 0;
    const int mcount = half ? (256 - mstart) : 128;
    const int c = t & 15;
    const bf16* Wh2 = a.Wb;

    const int iters = (mcount * 16 + 255) >> 8;
    for (int i = 0; i < iters; ++i) {
        int li = i * 256 + t;
        int mr = li >> 4;
        if (mr < mcount) {
            long ga = (long)(b * 256 + mstart + mr) * 1024 + jt * 128 + c * 8;
            *(int4*)&sh->a2.S[mr][c * 8] = *(const int4*)(Wh2 + ga);
        }
    }
    __syncthreads();

    if (t < 128) {
        int n = nbase + t;
        if (n > 0) {
            int cnt = n < (BAND - 1) ? n : (BAND - 1);
            int m0 = n - cnt;
            float f1n = a.f1b[b * 256 + n];
            float e[BAND - 1];
            float mx = -1e30f;
            for (int i = 0; i < cnt; ++i) {
                float vv = f1n + a.f2b[b * 256 + m0 + i];
                vv = vv > 0.f ? vv : ALPHA * vv;
                e[i] = vv; mx = fmaxf(mx, vv);
            }
            float ss = 0.f;
            for (int i = 0; i < cnt; ++i) { e[i] = __expf(e[i] - mx); ss += e[i]; }
            float inv = 1.0f / ss;
            for (int i = 0; i < cnt; ++i) sh->a2.att[t][i] = e[i] * inv;
        }
    }
    __syncthreads();

    for (int ln = wave; ln < 128; ln += 4) {
        int n = nbase + ln;
        if (n == 0) continue;
        int cnt = n < (BAND - 1) ? n : (BAND - 1);
        int mr0 = n - cnt - mstart;
        float s0 = 0.f, s1 = 0.f;
        for (int i = 0; i < cnt; ++i) {
            float aa = sh->a2.att[ln][i];
            unsigned u = *(const unsigned*)&sh->a2.S[mr0 + i][lane * 2];
            s0 += aa * bits2f((unsigned short)(u & 0xffff));
            s1 += aa * bits2f((unsigned short)(u >> 16));
        }
        s0 = s0 > 0.f ? s0 : expm1f(s0);
        s1 = s1 > 0.f ? s1 : expm1f(s1);
        unsigned out = (unsigned)f2bits(s0) | ((unsigned)f2bits(s1) << 16);
        *(unsigned*)(a.E + (long)(b * 256 + n) * 1024 + jt * 128 + lane * 2) = out;
    }
}

// ---- lgf vtask: 4 rows; writes logits + blocksum[v] (fence-free) ------------------
__device__ void lgf_task(int v, const MegaArgs& a, int t, int isb, ShU* sh) {
    const int wave = t >> 6, lane = t & 63;
    const int row = v * 4 + wave;
    const bf16* X = a.C;
    const bf16* ybase = (row & 255) ? a.E : a.C;
    float xv[16], yv[16];
    {
        const bf16* x = X + (long)row * 1024 + lane * 16;
        const bf16* y = ybase + (long)row * 1024 + lane * 16;
        union { int4 v4; unsigned short us[8]; } u0, u1, v0, v1;
        u0.v4 = *(const int4*)x; u1.v4 = *(const int4*)(x + 8);
        v0.v4 = *(const int4*)y; v1.v4 = *(const int4*)(y + 8);
        #pragma unroll
        for (int q = 0; q < 8; ++q) {
            xv[q] = bits2f(u0.us[q]); xv[q + 8] = bits2f(u1.us[q]);
            yv[q] = bits2f(v0.us[q]); yv[q + 8] = bits2f(v1.us[q]);
        }
    }
    float acc[NCLS];
    #pragma unroll
    for (int cc = 0; cc < NCLS; ++cc) {
        const float4* w1 = (const float4*)(a.W1T + (long)cc * 1024 + lane * 16);
        const float4* w2 = (const float4*)(a.W2T + (long)cc * 1024 + lane * 16);
        float s = 0.f;
        #pragma unroll
        for (int h = 0; h < 4; ++h) {
            float4 aa = w1[h], bb = w2[h];
            s += xv[h * 4 + 0] * aa.x + xv[h * 4 + 1] * aa.y + xv[h * 4 + 2] * aa.z + xv[h * 4 + 3] * aa.w;
            s += yv[h * 4 + 0] * bb.x + yv[h * 4 + 1] * bb.y + yv[h * 4 + 2] * bb.z + yv[h * 4 + 3] * bb.w;
        }
        acc[cc] = s;
    }
    #pragma unroll
    for (int cc = 0; cc < NCLS; ++cc)
        #pragma unroll
        for (int off = 32; off; off >>= 1) acc[cc] += __shfl_down(acc[cc], off);
    if (lane == 0) {
        float mx = -1e30f;
        #pragma unroll
        for (int cc = 0; cc < NCLS; ++cc) { acc[cc] += a.cvec[cc]; mx = fmaxf(mx, acc[cc]); }
        float s = 0.f;
        #pragma unroll
        for (int cc = 0; cc < NCLS; ++cc) { acc[cc] = expf(acc[cc] - mx); s += acc[cc]; }
        float inv = 1.0f / s;
        int lab = a.labels[row];
        float picked = 0.f;
        #pragma unroll
        for (int cc = 0; cc < NCLS; ++cc) {
            float pg = acc[cc] * inv;
            float vv = logf(0.5f * (pg + a.lhmm[(long)row * NCLS + cc]));
            long o = 1 + (long)row * NCLS + cc;
            if (isb) ((bf16*)a.out)[o] = tob(vv);
            else     ((float*)a.out)[o] = vv;
            if (cc == lab) picked = vv;
        }
        sh->ps[wave] = picked;
    }
    __syncthreads();
    if (t == 0) a.blocksum[v] = sh->ps[0] + sh->ps[1] + sh->ps[2] + sh->ps[3];
}

// =============================== THE MEGA-KERNEL ===================================
__global__ void __launch_bounds__(256, 2) mega_k(MegaArgs a) {
    __shared__ ShU sh;
    cg::grid_group grid = cg::this_grid();
    const int bx = blockIdx.x, t = threadIdx.x, G = gridDim.x;
    const int isb = probe_dev(a.pW, t, sh.sb);

    // ---- S1: smalls | transposes+gvec | convin | zero f1b/f2b ----
    if (bx == 0) smalls_task(a, t, isb);
    for (int v = bx; v < 2816; v += G) { prep_mid_task(v, a, t, isb, &sh); __syncthreads(); }
    if (!isb) {
        const long total = 2 * INEL / 8;
        for (long idx = (long)bx * 256 + t; idx < total; idx += (long)G * 256) {
            long i = idx * 8;
            const void* s; bf16* d; long off;
            if (i < INEL) { s = a.in_emo; d = a.Wb; off = i; }
            else          { s = a.in_cls; d = a.H2; off = i - INEL; }
            const float* f = (const float*)s + off;
            unsigned short tmp[8];
            #pragma unroll
            for (int q = 0; q < 8; ++q) tmp[q] = f2bits(f[q]);
            *(int4*)(d + off) = *(int4*)tmp;
        }
    }
    for (long i = (long)bx * 256 + t; i < 2 * M; i += (long)G * 256) a.f1b[i] = 0.f;
    grid.sync();

    // ---- S2: pooler GEMM, 1024 tiles (z=0: emo->E, z=1: cls->C), tanh+bias ----
    for (int v = bx; v < 1024; v += G) {
        int z = v >> 9, rem = v & 511;
        const bf16* A = z ? (isb ? (const bf16*)a.in_cls : a.H2)
                          : (isb ? (const bf16*)a.in_emo : a.Wb);
        bf16* Co = z ? a.C : a.E;
        gemm_pipe_core<1, 0>(A, Hh, a.wc + OFF_PWT, Hh, a.wc + OFF_PB, Co, Hh, Hh,
                             (rem & 63) * 128, (rem >> 6) * 128, sh.gemm);
        __syncthreads();
    }
    grid.sync();

    // ---- S3: Wh GEMM (512) + cls7 (2048) + w2 (128) + cvec (1) ----
    for (int v = bx; v < 2689; v += G) {
        if (v < 512)
            gemm_pipe_core<0, 0>(a.C, Hh, a.wc + OFF_WCT, Hh, (const bf16*)nullptr,
                                 a.Wb, Hh, Hh, (v & 63) * 128, (v >> 6) * 128, sh.gemm);
        else if (v < 2560)
            cls7_task(v - 512, a.E, a.wc + OFF_CWT, a.wc + OFF_CB, a.Bprob, t);
        else if (v < 2688)
            w2_task(v - 2560, a, t, isb, &sh);
        else
            cvec_task(a, t, isb);
        __syncthreads();
    }
    grid.sync();

    // ---- S4: att1 (512) + mean-row0 (256, first) ----
    for (int v = bx; v < 768; v += G) {
        att1_task(v, a.Wb, a.wc + OFF_GA1, a.wc + OFF_GA2, a.E, t, &sh);
        __syncthreads();
    }
    grid.sync();

    // ---- S5: Wh2 GEMM with fused f12 dots (512 tiles) ----
    for (int v = bx; v < 512; v += G) {
        gemm_pipe_core<0, 1>(a.E, Hh, a.wc + OFF_OWT, Hh, (const bf16*)nullptr,
                             a.Wb, Hh, Hh, (v & 63) * 128, (v >> 6) * 128, sh.gemm,
                             a.wc + OFF_OA1, a.wc + OFF_OA2, a.f1b, a.f2b);
        __syncthreads();
    }
    grid.sync();

    // ---- S6: att2 (512) + hmm (32) ----
    for (int v = bx; v < 544; v += G) {
        att2_hmm_task(v, a, t, &sh);
        __syncthreads();
    }
    grid.sync();

    // ---- S7: lgf (2048 vtasks of 4 rows) ----
    for (int v = bx; v < 2048; v += G) {
        lgf_task(v, a, t, isb, &sh);
        __syncthreads();
    }
    grid.sync();

    // ---- S8: loss reduce (block 0) ----
    if (bx == 0) {
        float s = 0.f;
        #pragma unroll
        for (int i = 0; i < 8; ++i) s += a.blocksum[t + i * 256];
        sh.red[t] = s; __syncthreads();
        for (int st = 128; st; st >>= 1) {
            if (t < st) sh.red[t] += sh.red[t + st];
            __syncthreads();
        }
        if (t == 0) {
            float v = -sh.red[0] / (float)(Bb * Nn);
            if (isb) ((bf16*)a.out)[0] = tob(v);
            else     ((float*)a.out)[0] = v;
        }
    }
}

extern "C" void kernel_launch(void* const* d_in, const int* in_sizes, int n_in,
                              void* d_out, int out_size, void* d_ws, size_t ws_size,
                              hipStream_t stream) {
    // ---- workspace layout (~78 MB) ----
    char* w = (char*)d_ws;
    bf16* C  = (bf16*)w;                       // fea_cls
    bf16* E  = C + INEL;                       // fea_emo -> h1 -> g
    bf16* Wb = E + INEL;                       // conv(emo) -> Wh -> Wh2
    bf16* H2 = Wb + INEL;                      // conv(cls)
    bf16* wc = H2 + INEL;                      // canonical weights
    float* f1b      = (float*)(wc + W_TOTAL);  // [M]
    float* f2b      = f1b + M;                 // [M]
    float* blocksum = f2b + M;                 // [2048]
    float* Bprob = blocksum + 2048;
    float* lhmm  = Bprob + (long)M * NCLS;
    float* W1f   = lhmm + (long)M * NCLS;      // [7][1024] f32
    float* W2f   = W1f + 7 * 1024;             // [7][1024] f32
    float* Gbf   = W2f + 7 * 1024;             // [1024][7] f32
    float* cvec  = Gbf + 1024 * 7;             // [7] f32

    MegaArgs a;
    a.pW = d_in[4];  a.pb = d_in[5];  a.gW = d_in[6];  a.ga1 = d_in[7];
    a.ga2 = d_in[8]; a.oW = d_in[9];  a.oa1 = d_in[10]; a.oa2 = d_in[11];
    a.l1W = d_in[12]; a.l1b = d_in[13]; a.l0W = d_in[14]; a.l0b = d_in[15];
    a.cW = d_in[16]; a.cb = d_in[17]; a.hA = d_in[18];
    a.in_emo = d_in[1]; a.in_cls = d_in[0];
    a.labels = (const int*)d_in[3];
    a.wc = wc; a.C = C; a.E = E; a.Wb = Wb; a.H2 = H2;
    a.f1b = f1b; a.f2b = f2b; a.blocksum = blocksum; a.Bprob = Bprob;
    a.lhmm = lhmm; a.W1T = W1f; a.W2T = W2f; a.Gb = Gbf; a.cvec = cvec;
    a.out = d_out;

    int maxB = 0;
    if (hipOccupancyMaxActiveBlocksPerMultiprocessor(&maxB, mega_k, 256, 0)
        != hipSuccess || maxB < 1) maxB = 1;
    int gridB = maxB * 256;                   // 256 CUs on MI355X
    if (gridB > 512) gridB = 512;             // all loops are grid-stride in G

    void* kargs[1] = { &a };
    (void)hipLaunchCooperativeKernel((const void*)mega_k, dim3(gridB), dim3(256),
                                     kargs, 0, stream);
}